// Round 2
// baseline (690.369 us; speedup 1.0000x reference)
//
#include <hip/hip_runtime.h>
#include <math.h>

#define NTOK   262144
#define DIM    64
#define NCODE  1024
#define LOSSOFF (NTOK*DIM)          // 16777216
#define IDXOFF  (NTOK*DIM + 1)      // indices written as float32

// ws layout (floats): [0,1024) = B[c] = fl32 sum(c^2); [1024,2048) = per-block loss partials

__global__ __launch_bounds__(256) void vq_prep(const float* __restrict__ cb,
                                               float* __restrict__ ws) {
    int c = blockIdx.x * 256 + threadIdx.x;
    if (c < NCODE) {
        const float4* p = (const float4*)(cb + (size_t)c * DIM);
        float a0 = 0.f, a1 = 0.f, a2 = 0.f, a3 = 0.f;
#pragma unroll
        for (int i = 0; i < 16; i++) {
            float4 v = p[i];
            a0 = fmaf(v.x, v.x, a0); a1 = fmaf(v.y, v.y, a1);
            a2 = fmaf(v.z, v.z, a2); a3 = fmaf(v.w, v.w, a3);
        }
        // exact order irrelevant: B uncertainty ~1e-12 vs rounding boundary 7.6e-6
        ws[c] = (a0 + a1) + (a2 + a3);
    }
}

__global__ __launch_bounds__(256) void vq_main(const float* __restrict__ x,
                                               const float* __restrict__ cb,
                                               float* __restrict__ out,
                                               float* __restrict__ ws) {
    const float* bn = ws;          // B[c]
    float* blk = ws + 1024;        // loss partials

    int t = blockIdx.x * 256 + threadIdx.x;

    float xv[DIM];
    {
        const float4* p = (const float4*)(x + (size_t)t * DIM);
#pragma unroll
        for (int i = 0; i < 16; i++) {
            float4 v = p[i];
            xv[4 * i] = v.x; xv[4 * i + 1] = v.y;
            xv[4 * i + 2] = v.z; xv[4 * i + 3] = v.w;
        }
    }

    // A = ||x||^2 : any fp32 order (uniform-shift invariance of the argmin)
    float a0 = 0.f, a1 = 0.f, a2 = 0.f, a3 = 0.f;
#pragma unroll
    for (int k = 0; k < DIM; k += 4) {
        a0 = fmaf(xv[k],     xv[k],     a0);
        a1 = fmaf(xv[k + 1], xv[k + 1], a1);
        a2 = fmaf(xv[k + 2], xv[k + 2], a2);
        a3 = fmaf(xv[k + 3], xv[k + 3], a3);
    }
    float A = (a0 + a1) + (a2 + a3);

    float best = 3.4e38f;
    int bidx = 0;
    // Replicate np/BLAS fp32 semantics: dot = sequential FMA chain k=0..63,
    // D = fl( fl(A + B[c]) - 2*dot )  (x2 exact, fma-contraction bit-identical)
    for (int c = 0; c < NCODE; c += 2) {
        const float4* c0 = (const float4*)(cb + (size_t)c * DIM);
        const float4* c1 = (const float4*)(cb + (size_t)(c + 1) * DIM);
        float p0 = 0.f, p1 = 0.f;
#pragma unroll
        for (int i = 0; i < 16; i++) {
            float4 u = c0[i], w = c1[i];
            p0 = fmaf(xv[4 * i + 0], u.x, p0); p1 = fmaf(xv[4 * i + 0], w.x, p1);
            p0 = fmaf(xv[4 * i + 1], u.y, p0); p1 = fmaf(xv[4 * i + 1], w.y, p1);
            p0 = fmaf(xv[4 * i + 2], u.z, p0); p1 = fmaf(xv[4 * i + 2], w.z, p1);
            p0 = fmaf(xv[4 * i + 3], u.w, p0); p1 = fmaf(xv[4 * i + 3], w.w, p1);
        }
        float s0 = A + bn[c];
        float s1 = A + bn[c + 1];
        float d0 = s0 - 2.0f * p0;
        float d1 = s1 - 2.0f * p1;
        // strict <, ascending c: np.argmin first-min semantics (d0 before d1)
        bool l0 = d0 < best;
        best = l0 ? d0 : best; bidx = l0 ? c : bidx;
        bool l1 = d1 < best;
        best = l1 ? d1 : best; bidx = l1 ? (c + 1) : bidx;
    }

    // epilogue: quantized = fl(x + fl(q - x)) (straight-through, ref-exact bits)
    float sqerr = 0.f;
    {
        const float4* qp = (const float4*)(cb + (size_t)bidx * DIM);
        float4* qo = (float4*)(out + (size_t)t * DIM);
#pragma unroll
        for (int i = 0; i < 16; i++) {
            float4 q = qp[i];
            float d0 = q.x - xv[4 * i + 0];
            float d1 = q.y - xv[4 * i + 1];
            float d2 = q.z - xv[4 * i + 2];
            float d3 = q.w - xv[4 * i + 3];
            float4 o;
            o.x = xv[4 * i + 0] + d0; o.y = xv[4 * i + 1] + d1;
            o.z = xv[4 * i + 2] + d2; o.w = xv[4 * i + 3] + d3;
            qo[i] = o;
            sqerr += d0 * d0 + d1 * d1 + d2 * d2 + d3 * d3;
        }
    }
    out[IDXOFF + t] = (float)bidx;

    // block loss partial
    for (int off = 32; off; off >>= 1) sqerr += __shfl_down(sqerr, off, 64);
    __shared__ float red[4];
    int lane = threadIdx.x & 63, wid = threadIdx.x >> 6;
    if (lane == 0) red[wid] = sqerr;
    __syncthreads();
    if (threadIdx.x == 0)
        blk[blockIdx.x] = (red[0] + red[1]) + (red[2] + red[3]);
}

__global__ __launch_bounds__(256) void vq_loss(float* __restrict__ out,
                                               const float* __restrict__ ws) {
    const float* blk = ws + 1024;
    __shared__ double sd[256];
    double s = 0.0;
    for (int i = threadIdx.x; i < 1024; i += 256) s += (double)blk[i];
    sd[threadIdx.x] = s;
    __syncthreads();
    for (int off = 128; off; off >>= 1) {
        if (threadIdx.x < off) sd[threadIdx.x] += sd[threadIdx.x + off];
        __syncthreads();
    }
    if (threadIdx.x == 0)
        out[LOSSOFF] = (float)(1.25 * sd[0] / ((double)NTOK * (double)DIM));
}

extern "C" void kernel_launch(void* const* d_in, const int* in_sizes, int n_in,
                              void* d_out, int out_size, void* d_ws, size_t ws_size,
                              hipStream_t stream) {
    (void)in_sizes; (void)n_in; (void)out_size; (void)ws_size;
    const float* x = (const float*)d_in[0];
    const float* cb = (const float*)d_in[1];
    float* out = (float*)d_out;
    float* ws = (float*)d_ws;

    hipLaunchKernelGGL(vq_prep, dim3(4), dim3(256), 0, stream, cb, ws);
    hipLaunchKernelGGL(vq_main, dim3(NTOK / 256), dim3(256), 0, stream, x, cb, out, ws);
    hipLaunchKernelGGL(vq_loss, dim3(1), dim3(256), 0, stream, out, ws);
}